// Round 13
// baseline (362.791 us; speedup 1.0000x reference)
//
#include <hip/hip_runtime.h>

// GAT 2-layer forward: R12 + (a) 4-way unrolled deg/scatter, (b) fused1/2
// deferred-inv (no rescale pass). N=100000, E=1.6M, L1: 8x8=64, L2: 1x16.

#define LRELU(v) ((v) > 0.f ? (v) : 0.2f * (v))
#define NEG_BIG -3.4e38f
#define SCAN_CHUNK 1024

__device__ __forceinline__ unsigned pk_bf16(float a, float b) {
  unsigned ua = __float_as_uint(a), ub = __float_as_uint(b);
  ua = (ua + 0x7fffu + ((ua >> 16) & 1u)) >> 16;
  ub = (ub + 0x7fffu + ((ub >> 16) & 1u)) >> 16;
  return ua | (ub << 16);
}
__device__ __forceinline__ float bf_sel(unsigned u, int hi) {
  return __uint_as_float(hi ? (u & 0xffff0000u) : (u << 16));
}

__global__ __launch_bounds__(256) void k_zero_i(int* __restrict__ p, int n) {
  int i = blockIdx.x * 256 + threadIdx.x;
  int stride = gridDim.x * 256;
  for (; i < n; i += stride) p[i] = 0;
}

// 4 edges/thread: 4 independent atomics in flight (latency hiding)
__global__ __launch_bounds__(256) void k_deg(const int* __restrict__ ei, int* __restrict__ deg,
                                             int* __restrict__ rank, int E) {
  const int tid = blockIdx.x * 256 + threadIdx.x;
  const int T = gridDim.x * 256;
#pragma unroll
  for (int i = 0; i < 4; ++i) {
    int e = tid + i * T;
    if (e < E) rank[e] = atomicAdd(&deg[ei[E + e]], 1);
  }
}

__global__ __launch_bounds__(256) void k_scan_part(const int* __restrict__ deg,
                                                   int* __restrict__ part, int N) {
  __shared__ int sm[256];
  const int t = threadIdx.x;
  const int base = blockIdx.x * SCAN_CHUNK + t * 4;
  int s = 0;
#pragma unroll
  for (int q = 0; q < 4; ++q) {
    int i = base + q;
    if (i < N) s += deg[i];
  }
  sm[t] = s;
  __syncthreads();
  for (int ofs = 128; ofs >= 1; ofs >>= 1) {
    if (t < ofs) sm[t] += sm[t + ofs];
    __syncthreads();
  }
  if (t == 0) part[blockIdx.x] = sm[0];
}

__global__ __launch_bounds__(256) void k_scan_top(int* __restrict__ part, int nb) {
  __shared__ int sm[256];
  const int t = threadIdx.x;
  sm[t] = (t < nb) ? part[t] : 0;
  __syncthreads();
  for (int ofs = 1; ofs < 256; ofs <<= 1) {
    int v = (t >= ofs) ? sm[t - ofs] : 0;
    __syncthreads();
    sm[t] += v;
    __syncthreads();
  }
  if (t < nb) part[t] = (t > 0) ? sm[t - 1] : 0;
}

__global__ __launch_bounds__(256) void k_scan_final(const int* __restrict__ deg,
                                                    const int* __restrict__ part,
                                                    int* __restrict__ off, int N, int E) {
  __shared__ int sm[256];
  const int t = threadIdx.x;
  const int base = blockIdx.x * SCAN_CHUNK + t * 4;
  int d[4];
  int s = 0;
#pragma unroll
  for (int q = 0; q < 4; ++q) {
    int i = base + q;
    d[q] = (i < N) ? deg[i] : 0;
    s += d[q];
  }
  sm[t] = s;
  __syncthreads();
  for (int ofs = 1; ofs < 256; ofs <<= 1) {
    int v = (t >= ofs) ? sm[t - ofs] : 0;
    __syncthreads();
    sm[t] += v;
    __syncthreads();
  }
  int run = part[blockIdx.x] + ((t > 0) ? sm[t - 1] : 0);
#pragma unroll
  for (int q = 0; q < 4; ++q) {
    int i = base + q;
    if (i < N) {
      off[i] = run;
      run += d[q];
    }
  }
  if (blockIdx.x == 0 && t == 0) off[N] = E;
}

// 4 edges/thread, atomic-free
__global__ __launch_bounds__(256) void k_scatter(const int* __restrict__ ei,
                                                 const int* __restrict__ off,
                                                 const int* __restrict__ rank,
                                                 int* __restrict__ csr, int E) {
  const int tid = blockIdx.x * 256 + threadIdx.x;
  const int T = gridDim.x * 256;
#pragma unroll
  for (int i = 0; i < 4; ++i) {
    int e = tid + i * T;
    if (e < E) csr[off[ei[E + e]] + rank[e]] = ei[e];
  }
}

// h1bf[N][32 u32] = bf16(x @ W1), fused a_s/a_d epilogue.
__global__ __launch_bounds__(256) void k_gemm1(const float* __restrict__ x,
                                               const float* __restrict__ W,
                                               const float* __restrict__ attS,
                                               const float* __restrict__ attD,
                                               unsigned* __restrict__ h1bf,
                                               float* __restrict__ a_s,
                                               float* __restrict__ a_d, int N) {
  __shared__ float sA[64][68];
  __shared__ float sW[64][64];
  const int t = threadIdx.x;
  const int n0 = blockIdx.x * 64;
  const int tr = t >> 4, tc = t & 15;
  const int tr4 = tr * 4, tc4 = tc * 4;

  float acc[4][4];
#pragma unroll
  for (int i = 0; i < 4; ++i)
#pragma unroll
    for (int j = 0; j < 4; ++j) acc[i][j] = 0.f;

  for (int c0 = 0; c0 < 256; c0 += 64) {
    {
      const int r = t >> 2, kq = (t & 3) * 16;
      const int n = n0 + r;
      float4 v[4];
      if (n < N) {
        const float4* xp = (const float4*)&x[(long)n * 256 + c0 + kq];
#pragma unroll
        for (int q = 0; q < 4; ++q) v[q] = xp[q];
      } else {
#pragma unroll
        for (int q = 0; q < 4; ++q) v[q] = make_float4(0.f, 0.f, 0.f, 0.f);
      }
#pragma unroll
      for (int q = 0; q < 4; ++q) {
        sA[kq + q * 4 + 0][r] = v[q].x;
        sA[kq + q * 4 + 1][r] = v[q].y;
        sA[kq + q * 4 + 2][r] = v[q].z;
        sA[kq + q * 4 + 3][r] = v[q].w;
      }
    }
#pragma unroll
    for (int i = 0; i < 4; ++i) {
      int idx = t + i * 256;
      int k = idx >> 4, col4 = (idx & 15) * 4;
      *(float4*)&sW[k][col4] = *(const float4*)&W[(long)(c0 + k) * 64 + col4];
    }
    __syncthreads();
#pragma unroll 16
    for (int k = 0; k < 64; ++k) {
      const float4 a = *(const float4*)&sA[k][tr4];
      const float4 b = *(const float4*)&sW[k][tc4];
      acc[0][0] += a.x * b.x; acc[0][1] += a.x * b.y; acc[0][2] += a.x * b.z; acc[0][3] += a.x * b.w;
      acc[1][0] += a.y * b.x; acc[1][1] += a.y * b.y; acc[1][2] += a.y * b.z; acc[1][3] += a.y * b.w;
      acc[2][0] += a.z * b.x; acc[2][1] += a.z * b.y; acc[2][2] += a.z * b.z; acc[2][3] += a.z * b.w;
      acc[3][0] += a.w * b.x; acc[3][1] += a.w * b.y; acc[3][2] += a.w * b.z; acc[3][3] += a.w * b.w;
    }
    __syncthreads();
  }

  const int head = tc >> 1;
  float attSv[4], attDv[4];
#pragma unroll
  for (int j = 0; j < 4; ++j) {
    int c7 = (tc4 + j) & 7;
    attSv[j] = attS[head * 8 + c7];
    attDv[j] = attD[head * 8 + c7];
  }
#pragma unroll
  for (int i = 0; i < 4; ++i) {
    const int n = n0 + tr4 + i;
    float ps = acc[i][0] * attSv[0] + acc[i][1] * attSv[1] + acc[i][2] * attSv[2] +
               acc[i][3] * attSv[3];
    float pd = acc[i][0] * attDv[0] + acc[i][1] * attDv[1] + acc[i][2] * attDv[2] +
               acc[i][3] * attDv[3];
    ps += __shfl_xor(ps, 1);
    pd += __shfl_xor(pd, 1);
    if (n < N) {
      h1bf[(long)n * 32 + tc * 2] = pk_bf16(acc[i][0], acc[i][1]);
      h1bf[(long)n * 32 + tc * 2 + 1] = pk_bf16(acc[i][2], acc[i][3]);
      if ((tc & 1) == 0) {
        a_s[n * 8 + head] = ps;
        a_d[n * 8 + head] = pd;
      }
    }
  }
}

// one wave per dst: (edge,head) softmax; tile holds UNNORMALIZED p; acc scaled
// once by invc = shfl(inv, head) at the end. Aggregation lane = col (R10).
__global__ __launch_bounds__(256) void k_fused1(const int* __restrict__ csr,
                                                const int* __restrict__ off,
                                                const float* __restrict__ as_,
                                                const float* __restrict__ ad_,
                                                const unsigned* __restrict__ h1bf,
                                                const float* __restrict__ b1,
                                                float* __restrict__ h1b, int N) {
  __shared__ float aT[4][8 * 72];  // [wave][h*72 + edge]
  __shared__ int sT[4][64];
  const int wid = threadIdx.x >> 6;
  float* alds = aT[wid];
  int* slds = sT[wid];

  int wave = (blockIdx.x * 256 + threadIdx.x) >> 6;
  if (wave >= N) return;
  const int lane = threadIdx.x & 63;
  const int d = wave;
  const int r0 = off[d];
  const int deg = off[d + 1] - r0;

  if (deg == 0) {
    float v = b1[lane];
    h1b[(long)d * 64 + lane] = v > 0.f ? v : __expf(v) - 1.f;
    return;
  }

  const int eidx = lane >> 3, h = lane & 7;
  const float adh = ad_[d * 8 + h];

  // pass 1: max over this lane's edges for head h
  float mh = NEG_BIG;
  for (int j = eidx; j < deg; j += 8) {
    int s = csr[r0 + j];
    float e = LRELU(as_[(long)s * 8 + h] + adh);
    mh = fmaxf(mh, e);
  }
  mh = fmaxf(mh, __shfl_xor(mh, 8));
  mh = fmaxf(mh, __shfl_xor(mh, 16));
  mh = fmaxf(mh, __shfl_xor(mh, 32));

  const int hbcol = (lane >> 3) * 72;  // head row for col 'lane'
  const int slot = lane >> 1;          // u32 slot with cols (2*slot, 2*slot+1)
  const int hi = lane & 1;
  float acc = 0.f;

  if (deg <= 64) {
    // sum pass builds tile with unnormalized p; no rescale pass
    float sum = 0.f;
    for (int j = eidx; j < deg; j += 8) {
      int s = csr[r0 + j];
      float e = LRELU(as_[(long)s * 8 + h] + adh);
      float p = __expf(e - mh);
      alds[h * 72 + j] = p;
      if (h == 0) slds[j] = s;
      sum += p;
    }
    sum += __shfl_xor(sum, 8);
    sum += __shfl_xor(sum, 16);
    sum += __shfl_xor(sum, 32);
    const float inv = 1.f / (sum + 1e-16f);
    const float invc = __shfl(inv, lane >> 3);  // inv of this col-lane's head
    __threadfence_block();

    int jj = 0;
    for (; jj + 4 <= deg; jj += 4) {
      int t0 = slds[jj], t1 = slds[jj + 1], t2 = slds[jj + 2], t3 = slds[jj + 3];
      float a0 = alds[hbcol + jj], a1 = alds[hbcol + jj + 1];
      float a2 = alds[hbcol + jj + 2], a3 = alds[hbcol + jj + 3];
      unsigned u0 = h1bf[(long)t0 * 32 + slot];
      unsigned u1 = h1bf[(long)t1 * 32 + slot];
      unsigned u2 = h1bf[(long)t2 * 32 + slot];
      unsigned u3 = h1bf[(long)t3 * 32 + slot];
      acc += a0 * bf_sel(u0, hi);
      acc += a1 * bf_sel(u1, hi);
      acc += a2 * bf_sel(u2, hi);
      acc += a3 * bf_sel(u3, hi);
    }
    for (; jj < deg; ++jj) {
      unsigned u = h1bf[(long)slds[jj] * 32 + slot];
      acc += alds[hbcol + jj] * bf_sel(u, hi);
    }
    acc *= invc;
  } else {
    // generic path (rare): sum pass, then per-chunk tile (normalized) + aggregate
    float sum = 0.f;
    for (int j = eidx; j < deg; j += 8) {
      int s = csr[r0 + j];
      float e = LRELU(as_[(long)s * 8 + h] + adh);
      sum += __expf(e - mh);
    }
    sum += __shfl_xor(sum, 8);
    sum += __shfl_xor(sum, 16);
    sum += __shfl_xor(sum, 32);
    const float inv = 1.f / (sum + 1e-16f);

    for (int j0 = 0; j0 < deg; j0 += 64) {
      const int cnt = min(64, deg - j0);
      for (int jj = eidx; jj < cnt; jj += 8) {
        int s = csr[r0 + j0 + jj];
        float e = LRELU(as_[(long)s * 8 + h] + adh);
        alds[h * 72 + jj] = __expf(e - mh) * inv;
        if (h == 0) slds[jj] = s;
      }
      __threadfence_block();

      int jj = 0;
      for (; jj + 4 <= cnt; jj += 4) {
        int t0 = slds[jj], t1 = slds[jj + 1], t2 = slds[jj + 2], t3 = slds[jj + 3];
        float a0 = alds[hbcol + jj], a1 = alds[hbcol + jj + 1];
        float a2 = alds[hbcol + jj + 2], a3 = alds[hbcol + jj + 3];
        unsigned u0 = h1bf[(long)t0 * 32 + slot];
        unsigned u1 = h1bf[(long)t1 * 32 + slot];
        unsigned u2 = h1bf[(long)t2 * 32 + slot];
        unsigned u3 = h1bf[(long)t3 * 32 + slot];
        acc += a0 * bf_sel(u0, hi);
        acc += a1 * bf_sel(u1, hi);
        acc += a2 * bf_sel(u2, hi);
        acc += a3 * bf_sel(u3, hi);
      }
      for (; jj < cnt; ++jj) {
        unsigned u = h1bf[(long)slds[jj] * 32 + slot];
        acc += alds[hbcol + jj] * bf_sel(u, hi);
      }
      __threadfence_block();
    }
  }
  float v = acc + b1[lane];
  h1b[(long)d * 64 + lane] = v > 0.f ? v : __expf(v) - 1.f;
}

// h2bf[N][8 u32] = bf16(h1b @ W2), fused attn2 epilogue (as2/ad2).
__global__ __launch_bounds__(256) void k_gemm2(const float* __restrict__ h1b,
                                               const float* __restrict__ W2,
                                               const float* __restrict__ attS,
                                               const float* __restrict__ attD,
                                               unsigned* __restrict__ h2bf,
                                               float* __restrict__ as2,
                                               float* __restrict__ ad2, int N) {
  __shared__ float sW[64][16];
  __shared__ float sX[16][64];
  const int t = threadIdx.x;
  const int n0 = blockIdx.x * 16;
  for (int i = t; i < 64 * 16; i += 256) sW[i >> 4][i & 15] = W2[i];
  for (int i = t; i < 16 * 64; i += 256) {
    int r = i >> 6, c = i & 63;
    int n = n0 + r;
    sX[r][c] = (n < N) ? h1b[(long)n * 64 + c] : 0.f;
  }
  __syncthreads();
  const int c = t & 15, r = t >> 4;
  float acc = 0.f;
#pragma unroll
  for (int k = 0; k < 64; ++k) acc += sX[r][k] * sW[k][c];
  const int n = n0 + r;
  float psum = acc * attS[c], dsum = acc * attD[c];
#pragma unroll
  for (int ofs = 1; ofs < 16; ofs <<= 1) {
    psum += __shfl_xor(psum, ofs);
    dsum += __shfl_xor(dsum, ofs);
  }
  float partner = __shfl_xor(acc, 1);
  if (n < N) {
    if ((c & 1) == 0) h2bf[(long)n * 8 + (c >> 1)] = pk_bf16(acc, partner);
    if (c == 0) {
      as2[n] = psum;
      ad2[n] = dsum;
    }
  }
}

// one wave per dst (R10): softmax + quarter-wave bf16 aggregation + lsm.
// Tile holds unnormalized p; acc scaled by inv once at end.
__global__ __launch_bounds__(256) void k_fused2(const int* __restrict__ csr,
                                                const int* __restrict__ off,
                                                const float* __restrict__ as_,
                                                const float* __restrict__ ad_,
                                                const unsigned* __restrict__ h2bf,
                                                const float* __restrict__ b2,
                                                float* __restrict__ out, int N) {
  __shared__ float aT[4][64];
  __shared__ int sT[4][64];
  const int wid = threadIdx.x >> 6;
  float* alds = aT[wid];
  int* slds = sT[wid];

  int wave = (blockIdx.x * 256 + threadIdx.x) >> 6;
  if (wave >= N) return;
  const int lane = threadIdx.x & 63;
  const int d = wave;
  const int r0 = off[d];
  const int deg = off[d + 1] - r0;
  const float add = ad_[d];

  float em = NEG_BIG, e0 = NEG_BIG;
  int s0 = 0;
  for (int j0 = 0; j0 < deg; j0 += 64) {
    int j = j0 + lane;
    float e = NEG_BIG;
    int s = 0;
    if (j < deg) {
      s = csr[r0 + j];
      e = LRELU(as_[s] + add);
    }
    if (j0 == 0) { e0 = e; s0 = s; }
    em = fmaxf(em, e);
  }
#pragma unroll
  for (int ofs = 32; ofs >= 1; ofs >>= 1) em = fmaxf(em, __shfl_xor(em, ofs));

  float p0 = (deg > 0) ? __expf(e0 - em) : 0.f;
  float sm = p0;
  for (int j0 = 64; j0 < deg; j0 += 64) {
    int j = j0 + lane;
    if (j < deg) sm += __expf(LRELU(as_[csr[r0 + j]] + add) - em);
  }
#pragma unroll
  for (int ofs = 32; ofs >= 1; ofs >>= 1) sm += __shfl_xor(sm, ofs);
  const float inv = 1.f / (sm + 1e-16f);

  const int sub = lane >> 4, col = lane & 15;
  const int slot = col >> 1, hi = col & 1;
  float acc = 0.f;
  for (int j0 = 0; j0 < deg; j0 += 64) {
    float p;
    int s;
    if (j0 == 0) {
      p = p0;
      s = s0;
    } else {
      int j = j0 + lane;
      p = 0.f;
      s = 0;
      if (j < deg) {
        s = csr[r0 + j];
        p = __expf(LRELU(as_[s] + add) - em);
      }
    }
    alds[lane] = p;  // unnormalized
    slds[lane] = s;
    __threadfence_block();

    const int cnt = min(64, deg - j0);
    int j = sub;
    for (; j + 4 < cnt; j += 8) {
      int t0 = slds[j], t1 = slds[j + 4];
      float a0 = alds[j], a1 = alds[j + 4];
      unsigned u0 = h2bf[(long)t0 * 8 + slot];
      unsigned u1 = h2bf[(long)t1 * 8 + slot];
      acc += a0 * bf_sel(u0, hi) + a1 * bf_sel(u1, hi);
    }
    for (; j < cnt; j += 4) {
      unsigned u = h2bf[(long)slds[j] * 8 + slot];
      acc += alds[j] * bf_sel(u, hi);
    }
    __threadfence_block();
  }
  acc += __shfl_xor(acc, 16);
  acc += __shfl_xor(acc, 32);
  acc *= inv;

  float v = acc + b2[col];
  float mm = v;
#pragma unroll
  for (int ofs = 1; ofs < 16; ofs <<= 1) mm = fmaxf(mm, __shfl_xor(mm, ofs));
  float ex = __expf(v - mm), ssum = ex;
#pragma unroll
  for (int ofs = 1; ofs < 16; ofs <<= 1) ssum += __shfl_xor(ssum, ofs);
  if (sub == 0) out[(long)d * 16 + col] = v - (mm + __logf(ssum));
}

extern "C" void kernel_launch(void* const* d_in, const int* in_sizes, int n_in,
                              void* d_out, int out_size, void* d_ws, size_t ws_size,
                              hipStream_t stream) {
  const float* x = (const float*)d_in[0];
  const int* ei = (const int*)d_in[1];
  const float* W1 = (const float*)d_in[2];
  const float* attS1 = (const float*)d_in[3];
  const float* attD1 = (const float*)d_in[4];
  const float* b1 = (const float*)d_in[5];
  const float* W2 = (const float*)d_in[6];
  const float* attS2 = (const float*)d_in[7];
  const float* attD2 = (const float*)d_in[8];
  const float* b2 = (const float*)d_in[9];
  float* out = (float*)d_out;

  const int N = in_sizes[0] / 256;
  const int E = in_sizes[1] / 2;

  // ws layout in 4-byte WORDS:
  // [0,32N): h1bf (N x 32 u32)
  // [32N,96N): h1b fp32 (N x 64)
  // [96N,112N): rank (E=16N ints) -> dead after scatter; overlaid:
  //   h2bf [96N,104N) (N x 8 u32), as2 [104N,105N), ad2 [105N,106N)
  // [112N,128N): csr (16N ints)
  // [128N,130N): off   [130N,131N): deg   [131N,132N): part
  float* ws = (float*)d_ws;
  unsigned* h1bf = (unsigned*)ws;
  float* h1b = ws + (long)32 * N;
  int* rank = (int*)(ws + (long)96 * N);
  unsigned* h2bf = (unsigned*)(ws + (long)96 * N);
  float* as2 = ws + (long)104 * N;
  float* ad2 = ws + (long)105 * N;
  int* csr = (int*)(ws + (long)112 * N);
  int* off = (int*)(ws + (long)128 * N);
  int* deg = (int*)(ws + (long)130 * N);
  int* part = (int*)(ws + (long)131 * N);

  float* as1 = out;
  float* ad1 = out + (long)8 * N;

  const int EB4 = (E + 1023) / 1024;
  const int NB = (N + SCAN_CHUNK - 1) / SCAN_CHUNK;

  k_zero_i<<<512, 256, 0, stream>>>(deg, N);
  k_deg<<<EB4, 256, 0, stream>>>(ei, deg, rank, E);
  k_scan_part<<<NB, 256, 0, stream>>>(deg, part, N);
  k_scan_top<<<1, 256, 0, stream>>>(part, NB);
  k_scan_final<<<NB, 256, 0, stream>>>(deg, part, off, N, E);
  k_scatter<<<EB4, 256, 0, stream>>>(ei, off, rank, csr, E);

  k_gemm1<<<(N + 63) / 64, 256, 0, stream>>>(x, W1, attS1, attD1, h1bf, as1, ad1, N);
  k_fused1<<<(N + 3) / 4, 256, 0, stream>>>(csr, off, as1, ad1, h1bf, b1, h1b, N);

  k_gemm2<<<(N + 15) / 16, 256, 0, stream>>>(h1b, W2, attS2, attD2, h2bf, as2, ad2, N);
  k_fused2<<<(N + 3) / 4, 256, 0, stream>>>(csr, off, as2, ad2, h2bf, b2, out, N);
}

// Round 14
// 340.267 us; speedup vs baseline: 1.0662x; 1.0662x over previous
//
#include <hip/hip_runtime.h>

// GAT 2-layer forward: R13 fused1/2 (deferred-inv) + 1-edge/thread deg/scatter
// (R12-proven) + heterogeneous gemm1||scatter fusion.
// N=100000, E=1.6M, L1: 8x8=64, L2: 1x16.

#define LRELU(v) ((v) > 0.f ? (v) : 0.2f * (v))
#define NEG_BIG -3.4e38f
#define SCAN_CHUNK 1024

__device__ __forceinline__ unsigned pk_bf16(float a, float b) {
  unsigned ua = __float_as_uint(a), ub = __float_as_uint(b);
  ua = (ua + 0x7fffu + ((ua >> 16) & 1u)) >> 16;
  ub = (ub + 0x7fffu + ((ub >> 16) & 1u)) >> 16;
  return ua | (ub << 16);
}
__device__ __forceinline__ float bf_sel(unsigned u, int hi) {
  return __uint_as_float(hi ? (u & 0xffff0000u) : (u << 16));
}

__global__ __launch_bounds__(256) void k_zero_i(int* __restrict__ p, int n) {
  int i = blockIdx.x * 256 + threadIdx.x;
  int stride = gridDim.x * 256;
  for (; i < n; i += stride) p[i] = 0;
}

// 1 edge/thread: max waves in flight (R13 lesson: TLP > ILP for atomics)
__global__ __launch_bounds__(256) void k_deg(const int* __restrict__ ei, int* __restrict__ deg,
                                             int* __restrict__ rank, int E) {
  int e = blockIdx.x * 256 + threadIdx.x;
  if (e >= E) return;
  rank[e] = atomicAdd(&deg[ei[E + e]], 1);
}

__global__ __launch_bounds__(256) void k_scan_part(const int* __restrict__ deg,
                                                   int* __restrict__ part, int N) {
  __shared__ int sm[256];
  const int t = threadIdx.x;
  const int base = blockIdx.x * SCAN_CHUNK + t * 4;
  int s = 0;
#pragma unroll
  for (int q = 0; q < 4; ++q) {
    int i = base + q;
    if (i < N) s += deg[i];
  }
  sm[t] = s;
  __syncthreads();
  for (int ofs = 128; ofs >= 1; ofs >>= 1) {
    if (t < ofs) sm[t] += sm[t + ofs];
    __syncthreads();
  }
  if (t == 0) part[blockIdx.x] = sm[0];
}

__global__ __launch_bounds__(256) void k_scan_top(int* __restrict__ part, int nb) {
  __shared__ int sm[256];
  const int t = threadIdx.x;
  sm[t] = (t < nb) ? part[t] : 0;
  __syncthreads();
  for (int ofs = 1; ofs < 256; ofs <<= 1) {
    int v = (t >= ofs) ? sm[t - ofs] : 0;
    __syncthreads();
    sm[t] += v;
    __syncthreads();
  }
  if (t < nb) part[t] = (t > 0) ? sm[t - 1] : 0;
}

__global__ __launch_bounds__(256) void k_scan_final(const int* __restrict__ deg,
                                                    const int* __restrict__ part,
                                                    int* __restrict__ off, int N, int E) {
  __shared__ int sm[256];
  const int t = threadIdx.x;
  const int base = blockIdx.x * SCAN_CHUNK + t * 4;
  int d[4];
  int s = 0;
#pragma unroll
  for (int q = 0; q < 4; ++q) {
    int i = base + q;
    d[q] = (i < N) ? deg[i] : 0;
    s += d[q];
  }
  sm[t] = s;
  __syncthreads();
  for (int ofs = 1; ofs < 256; ofs <<= 1) {
    int v = (t >= ofs) ? sm[t - ofs] : 0;
    __syncthreads();
    sm[t] += v;
    __syncthreads();
  }
  int run = part[blockIdx.x] + ((t > 0) ? sm[t - 1] : 0);
#pragma unroll
  for (int q = 0; q < 4; ++q) {
    int i = base + q;
    if (i < N) {
      off[i] = run;
      run += d[q];
    }
  }
  if (blockIdx.x == 0 && t == 0) off[N] = E;
}

// Heterogeneous: blocks [0,G1) = gemm1 (h1bf + a_s/a_d epilogue);
// blocks [G1, G1+EB) = scatter (1 edge/thread, atomic-free).
// Independent work; branch is block-uniform so gemm1's barriers are safe.
__global__ __launch_bounds__(256) void k_g1s(const float* __restrict__ x,
                                             const float* __restrict__ W,
                                             const float* __restrict__ attS,
                                             const float* __restrict__ attD,
                                             unsigned* __restrict__ h1bf,
                                             float* __restrict__ a_s,
                                             float* __restrict__ a_d, int N, int G1,
                                             const int* __restrict__ ei,
                                             const int* __restrict__ off,
                                             const int* __restrict__ rank,
                                             int* __restrict__ csr, int E) {
  __shared__ float sA[64][68];
  __shared__ float sW[64][64];
  const int t = threadIdx.x;

  if (blockIdx.x >= G1) {
    int e = (blockIdx.x - G1) * 256 + t;
    if (e < E) csr[off[ei[E + e]] + rank[e]] = ei[e];
    return;
  }

  const int n0 = blockIdx.x * 64;
  const int tr = t >> 4, tc = t & 15;
  const int tr4 = tr * 4, tc4 = tc * 4;

  float acc[4][4];
#pragma unroll
  for (int i = 0; i < 4; ++i)
#pragma unroll
    for (int j = 0; j < 4; ++j) acc[i][j] = 0.f;

  for (int c0 = 0; c0 < 256; c0 += 64) {
    {
      const int r = t >> 2, kq = (t & 3) * 16;
      const int n = n0 + r;
      float4 v[4];
      if (n < N) {
        const float4* xp = (const float4*)&x[(long)n * 256 + c0 + kq];
#pragma unroll
        for (int q = 0; q < 4; ++q) v[q] = xp[q];
      } else {
#pragma unroll
        for (int q = 0; q < 4; ++q) v[q] = make_float4(0.f, 0.f, 0.f, 0.f);
      }
#pragma unroll
      for (int q = 0; q < 4; ++q) {
        sA[kq + q * 4 + 0][r] = v[q].x;
        sA[kq + q * 4 + 1][r] = v[q].y;
        sA[kq + q * 4 + 2][r] = v[q].z;
        sA[kq + q * 4 + 3][r] = v[q].w;
      }
    }
#pragma unroll
    for (int i = 0; i < 4; ++i) {
      int idx = t + i * 256;
      int k = idx >> 4, col4 = (idx & 15) * 4;
      *(float4*)&sW[k][col4] = *(const float4*)&W[(long)(c0 + k) * 64 + col4];
    }
    __syncthreads();
#pragma unroll 16
    for (int k = 0; k < 64; ++k) {
      const float4 a = *(const float4*)&sA[k][tr4];
      const float4 b = *(const float4*)&sW[k][tc4];
      acc[0][0] += a.x * b.x; acc[0][1] += a.x * b.y; acc[0][2] += a.x * b.z; acc[0][3] += a.x * b.w;
      acc[1][0] += a.y * b.x; acc[1][1] += a.y * b.y; acc[1][2] += a.y * b.z; acc[1][3] += a.y * b.w;
      acc[2][0] += a.z * b.x; acc[2][1] += a.z * b.y; acc[2][2] += a.z * b.z; acc[2][3] += a.z * b.w;
      acc[3][0] += a.w * b.x; acc[3][1] += a.w * b.y; acc[3][2] += a.w * b.z; acc[3][3] += a.w * b.w;
    }
    __syncthreads();
  }

  const int head = tc >> 1;
  float attSv[4], attDv[4];
#pragma unroll
  for (int j = 0; j < 4; ++j) {
    int c7 = (tc4 + j) & 7;
    attSv[j] = attS[head * 8 + c7];
    attDv[j] = attD[head * 8 + c7];
  }
#pragma unroll
  for (int i = 0; i < 4; ++i) {
    const int n = n0 + tr4 + i;
    float ps = acc[i][0] * attSv[0] + acc[i][1] * attSv[1] + acc[i][2] * attSv[2] +
               acc[i][3] * attSv[3];
    float pd = acc[i][0] * attDv[0] + acc[i][1] * attDv[1] + acc[i][2] * attDv[2] +
               acc[i][3] * attDv[3];
    ps += __shfl_xor(ps, 1);
    pd += __shfl_xor(pd, 1);
    if (n < N) {
      h1bf[(long)n * 32 + tc * 2] = pk_bf16(acc[i][0], acc[i][1]);
      h1bf[(long)n * 32 + tc * 2 + 1] = pk_bf16(acc[i][2], acc[i][3]);
      if ((tc & 1) == 0) {
        a_s[n * 8 + head] = ps;
        a_d[n * 8 + head] = pd;
      }
    }
  }
}

// one wave per dst: (edge,head) softmax; tile holds UNNORMALIZED p; acc scaled
// once by invc = shfl(inv, head) at the end. Aggregation lane = col.
__global__ __launch_bounds__(256) void k_fused1(const int* __restrict__ csr,
                                                const int* __restrict__ off,
                                                const float* __restrict__ as_,
                                                const float* __restrict__ ad_,
                                                const unsigned* __restrict__ h1bf,
                                                const float* __restrict__ b1,
                                                float* __restrict__ h1b, int N) {
  __shared__ float aT[4][8 * 72];  // [wave][h*72 + edge]
  __shared__ int sT[4][64];
  const int wid = threadIdx.x >> 6;
  float* alds = aT[wid];
  int* slds = sT[wid];

  int wave = (blockIdx.x * 256 + threadIdx.x) >> 6;
  if (wave >= N) return;
  const int lane = threadIdx.x & 63;
  const int d = wave;
  const int r0 = off[d];
  const int deg = off[d + 1] - r0;

  if (deg == 0) {
    float v = b1[lane];
    h1b[(long)d * 64 + lane] = v > 0.f ? v : __expf(v) - 1.f;
    return;
  }

  const int eidx = lane >> 3, h = lane & 7;
  const float adh = ad_[d * 8 + h];

  float mh = NEG_BIG;
  for (int j = eidx; j < deg; j += 8) {
    int s = csr[r0 + j];
    float e = LRELU(as_[(long)s * 8 + h] + adh);
    mh = fmaxf(mh, e);
  }
  mh = fmaxf(mh, __shfl_xor(mh, 8));
  mh = fmaxf(mh, __shfl_xor(mh, 16));
  mh = fmaxf(mh, __shfl_xor(mh, 32));

  const int hbcol = (lane >> 3) * 72;
  const int slot = lane >> 1;
  const int hi = lane & 1;
  float acc = 0.f;

  if (deg <= 64) {
    float sum = 0.f;
    for (int j = eidx; j < deg; j += 8) {
      int s = csr[r0 + j];
      float e = LRELU(as_[(long)s * 8 + h] + adh);
      float p = __expf(e - mh);
      alds[h * 72 + j] = p;
      if (h == 0) slds[j] = s;
      sum += p;
    }
    sum += __shfl_xor(sum, 8);
    sum += __shfl_xor(sum, 16);
    sum += __shfl_xor(sum, 32);
    const float inv = 1.f / (sum + 1e-16f);
    const float invc = __shfl(inv, lane >> 3);
    __threadfence_block();

    int jj = 0;
    for (; jj + 4 <= deg; jj += 4) {
      int t0 = slds[jj], t1 = slds[jj + 1], t2 = slds[jj + 2], t3 = slds[jj + 3];
      float a0 = alds[hbcol + jj], a1 = alds[hbcol + jj + 1];
      float a2 = alds[hbcol + jj + 2], a3 = alds[hbcol + jj + 3];
      unsigned u0 = h1bf[(long)t0 * 32 + slot];
      unsigned u1 = h1bf[(long)t1 * 32 + slot];
      unsigned u2 = h1bf[(long)t2 * 32 + slot];
      unsigned u3 = h1bf[(long)t3 * 32 + slot];
      acc += a0 * bf_sel(u0, hi);
      acc += a1 * bf_sel(u1, hi);
      acc += a2 * bf_sel(u2, hi);
      acc += a3 * bf_sel(u3, hi);
    }
    for (; jj < deg; ++jj) {
      unsigned u = h1bf[(long)slds[jj] * 32 + slot];
      acc += alds[hbcol + jj] * bf_sel(u, hi);
    }
    acc *= invc;
  } else {
    float sum = 0.f;
    for (int j = eidx; j < deg; j += 8) {
      int s = csr[r0 + j];
      float e = LRELU(as_[(long)s * 8 + h] + adh);
      sum += __expf(e - mh);
    }
    sum += __shfl_xor(sum, 8);
    sum += __shfl_xor(sum, 16);
    sum += __shfl_xor(sum, 32);
    const float inv = 1.f / (sum + 1e-16f);

    for (int j0 = 0; j0 < deg; j0 += 64) {
      const int cnt = min(64, deg - j0);
      for (int jj = eidx; jj < cnt; jj += 8) {
        int s = csr[r0 + j0 + jj];
        float e = LRELU(as_[(long)s * 8 + h] + adh);
        alds[h * 72 + jj] = __expf(e - mh) * inv;
        if (h == 0) slds[jj] = s;
      }
      __threadfence_block();

      int jj = 0;
      for (; jj + 4 <= cnt; jj += 4) {
        int t0 = slds[jj], t1 = slds[jj + 1], t2 = slds[jj + 2], t3 = slds[jj + 3];
        float a0 = alds[hbcol + jj], a1 = alds[hbcol + jj + 1];
        float a2 = alds[hbcol + jj + 2], a3 = alds[hbcol + jj + 3];
        unsigned u0 = h1bf[(long)t0 * 32 + slot];
        unsigned u1 = h1bf[(long)t1 * 32 + slot];
        unsigned u2 = h1bf[(long)t2 * 32 + slot];
        unsigned u3 = h1bf[(long)t3 * 32 + slot];
        acc += a0 * bf_sel(u0, hi);
        acc += a1 * bf_sel(u1, hi);
        acc += a2 * bf_sel(u2, hi);
        acc += a3 * bf_sel(u3, hi);
      }
      for (; jj < cnt; ++jj) {
        unsigned u = h1bf[(long)slds[jj] * 32 + slot];
        acc += alds[hbcol + jj] * bf_sel(u, hi);
      }
      __threadfence_block();
    }
  }
  float v = acc + b1[lane];
  h1b[(long)d * 64 + lane] = v > 0.f ? v : __expf(v) - 1.f;
}

// h2bf[N][8 u32] = bf16(h1b @ W2), fused attn2 epilogue (as2/ad2).
__global__ __launch_bounds__(256) void k_gemm2(const float* __restrict__ h1b,
                                               const float* __restrict__ W2,
                                               const float* __restrict__ attS,
                                               const float* __restrict__ attD,
                                               unsigned* __restrict__ h2bf,
                                               float* __restrict__ as2,
                                               float* __restrict__ ad2, int N) {
  __shared__ float sW[64][16];
  __shared__ float sX[16][64];
  const int t = threadIdx.x;
  const int n0 = blockIdx.x * 16;
  for (int i = t; i < 64 * 16; i += 256) sW[i >> 4][i & 15] = W2[i];
  for (int i = t; i < 16 * 64; i += 256) {
    int r = i >> 6, c = i & 63;
    int n = n0 + r;
    sX[r][c] = (n < N) ? h1b[(long)n * 64 + c] : 0.f;
  }
  __syncthreads();
  const int c = t & 15, r = t >> 4;
  float acc = 0.f;
#pragma unroll
  for (int k = 0; k < 64; ++k) acc += sX[r][k] * sW[k][c];
  const int n = n0 + r;
  float psum = acc * attS[c], dsum = acc * attD[c];
#pragma unroll
  for (int ofs = 1; ofs < 16; ofs <<= 1) {
    psum += __shfl_xor(psum, ofs);
    dsum += __shfl_xor(dsum, ofs);
  }
  float partner = __shfl_xor(acc, 1);
  if (n < N) {
    if ((c & 1) == 0) h2bf[(long)n * 8 + (c >> 1)] = pk_bf16(acc, partner);
    if (c == 0) {
      as2[n] = psum;
      ad2[n] = dsum;
    }
  }
}

// one wave per dst: softmax + quarter-wave bf16 aggregation + lsm (deferred inv)
__global__ __launch_bounds__(256) void k_fused2(const int* __restrict__ csr,
                                                const int* __restrict__ off,
                                                const float* __restrict__ as_,
                                                const float* __restrict__ ad_,
                                                const unsigned* __restrict__ h2bf,
                                                const float* __restrict__ b2,
                                                float* __restrict__ out, int N) {
  __shared__ float aT[4][64];
  __shared__ int sT[4][64];
  const int wid = threadIdx.x >> 6;
  float* alds = aT[wid];
  int* slds = sT[wid];

  int wave = (blockIdx.x * 256 + threadIdx.x) >> 6;
  if (wave >= N) return;
  const int lane = threadIdx.x & 63;
  const int d = wave;
  const int r0 = off[d];
  const int deg = off[d + 1] - r0;
  const float add = ad_[d];

  float em = NEG_BIG, e0 = NEG_BIG;
  int s0 = 0;
  for (int j0 = 0; j0 < deg; j0 += 64) {
    int j = j0 + lane;
    float e = NEG_BIG;
    int s = 0;
    if (j < deg) {
      s = csr[r0 + j];
      e = LRELU(as_[s] + add);
    }
    if (j0 == 0) { e0 = e; s0 = s; }
    em = fmaxf(em, e);
  }
#pragma unroll
  for (int ofs = 32; ofs >= 1; ofs >>= 1) em = fmaxf(em, __shfl_xor(em, ofs));

  float p0 = (deg > 0) ? __expf(e0 - em) : 0.f;
  float sm = p0;
  for (int j0 = 64; j0 < deg; j0 += 64) {
    int j = j0 + lane;
    if (j < deg) sm += __expf(LRELU(as_[csr[r0 + j]] + add) - em);
  }
#pragma unroll
  for (int ofs = 32; ofs >= 1; ofs >>= 1) sm += __shfl_xor(sm, ofs);
  const float inv = 1.f / (sm + 1e-16f);

  const int sub = lane >> 4, col = lane & 15;
  const int slot = col >> 1, hi = col & 1;
  float acc = 0.f;
  for (int j0 = 0; j0 < deg; j0 += 64) {
    float p;
    int s;
    if (j0 == 0) {
      p = p0;
      s = s0;
    } else {
      int j = j0 + lane;
      p = 0.f;
      s = 0;
      if (j < deg) {
        s = csr[r0 + j];
        p = __expf(LRELU(as_[s] + add) - em);
      }
    }
    alds[lane] = p;  // unnormalized
    slds[lane] = s;
    __threadfence_block();

    const int cnt = min(64, deg - j0);
    int j = sub;
    for (; j + 4 < cnt; j += 8) {
      int t0 = slds[j], t1 = slds[j + 4];
      float a0 = alds[j], a1 = alds[j + 4];
      unsigned u0 = h2bf[(long)t0 * 8 + slot];
      unsigned u1 = h2bf[(long)t1 * 8 + slot];
      acc += a0 * bf_sel(u0, hi) + a1 * bf_sel(u1, hi);
    }
    for (; j < cnt; j += 4) {
      unsigned u = h2bf[(long)slds[j] * 8 + slot];
      acc += alds[j] * bf_sel(u, hi);
    }
    __threadfence_block();
  }
  acc += __shfl_xor(acc, 16);
  acc += __shfl_xor(acc, 32);
  acc *= inv;

  float v = acc + b2[col];
  float mm = v;
#pragma unroll
  for (int ofs = 1; ofs < 16; ofs <<= 1) mm = fmaxf(mm, __shfl_xor(mm, ofs));
  float ex = __expf(v - mm), ssum = ex;
#pragma unroll
  for (int ofs = 1; ofs < 16; ofs <<= 1) ssum += __shfl_xor(ssum, ofs);
  if (sub == 0) out[(long)d * 16 + col] = v - (mm + __logf(ssum));
}

extern "C" void kernel_launch(void* const* d_in, const int* in_sizes, int n_in,
                              void* d_out, int out_size, void* d_ws, size_t ws_size,
                              hipStream_t stream) {
  const float* x = (const float*)d_in[0];
  const int* ei = (const int*)d_in[1];
  const float* W1 = (const float*)d_in[2];
  const float* attS1 = (const float*)d_in[3];
  const float* attD1 = (const float*)d_in[4];
  const float* b1 = (const float*)d_in[5];
  const float* W2 = (const float*)d_in[6];
  const float* attS2 = (const float*)d_in[7];
  const float* attD2 = (const float*)d_in[8];
  const float* b2 = (const float*)d_in[9];
  float* out = (float*)d_out;

  const int N = in_sizes[0] / 256;
  const int E = in_sizes[1] / 2;

  // ws layout in 4-byte WORDS:
  // [0,32N): h1bf (N x 32 u32)
  // [32N,96N): h1b fp32 (N x 64)
  // [96N,112N): rank (E=16N ints) -> dead after scatter; overlaid:
  //   h2bf [96N,104N) (N x 8 u32), as2 [104N,105N), ad2 [105N,106N)
  // [112N,128N): csr (16N ints)
  // [128N,130N): off   [130N,131N): deg   [131N,132N): part
  float* ws = (float*)d_ws;
  unsigned* h1bf = (unsigned*)ws;
  float* h1b = ws + (long)32 * N;
  int* rank = (int*)(ws + (long)96 * N);
  unsigned* h2bf = (unsigned*)(ws + (long)96 * N);
  float* as2 = ws + (long)104 * N;
  float* ad2 = ws + (long)105 * N;
  int* csr = (int*)(ws + (long)112 * N);
  int* off = (int*)(ws + (long)128 * N);
  int* deg = (int*)(ws + (long)130 * N);
  int* part = (int*)(ws + (long)131 * N);

  float* as1 = out;
  float* ad1 = out + (long)8 * N;

  const int EB = (E + 255) / 256;
  const int NB = (N + SCAN_CHUNK - 1) / SCAN_CHUNK;
  const int G1 = (N + 63) / 64;

  k_zero_i<<<512, 256, 0, stream>>>(deg, N);
  k_deg<<<EB, 256, 0, stream>>>(ei, deg, rank, E);
  k_scan_part<<<NB, 256, 0, stream>>>(deg, part, N);
  k_scan_top<<<1, 256, 0, stream>>>(part, NB);
  k_scan_final<<<NB, 256, 0, stream>>>(deg, part, off, N, E);

  // fused gemm1 || scatter (independent work, one dispatch)
  k_g1s<<<G1 + EB, 256, 0, stream>>>(x, W1, attS1, attD1, h1bf, as1, ad1, N, G1,
                                     ei, off, rank, csr, E);

  k_fused1<<<(N + 3) / 4, 256, 0, stream>>>(csr, off, as1, ad1, h1bf, b1, h1b, N);

  k_gemm2<<<(N + 15) / 16, 256, 0, stream>>>(h1b, W2, attS2, attD2, h2bf, as2, ad2, N);
  k_fused2<<<(N + 3) / 4, 256, 0, stream>>>(csr, off, as2, ad2, h2bf, b2, out, N);
}